// Round 18
// baseline (664.963 us; speedup 1.0000x reference)
//
#include <hip/hip_runtime.h>

#define NPTS 4096
#define EPSF 1e-5f

// ---------------- sortable-key helpers ----------------
__device__ __forceinline__ unsigned f2u(float f) {
  unsigned b = __float_as_uint(f);
  return (b & 0x80000000u) ? ~b : (b | 0x80000000u);
}
__device__ __forceinline__ float u2f(unsigned u) {
  unsigned b = (u & 0x80000000u) ? (u & 0x7fffffffu) : ~u;
  return __uint_as_float(b);
}
__device__ __forceinline__ unsigned shflx(unsigned v, int j) {
  return (unsigned)__shfl_xor((int)v, j);
}
__device__ __forceinline__ unsigned long long shflx64(unsigned long long v, int j) {
  unsigned lo = (unsigned)__shfl_xor((int)(unsigned)(v & 0xffffffffull), j);
  unsigned hi = (unsigned)__shfl_xor((int)(unsigned)(v >> 32), j);
  return ((unsigned long long)hi << 32) | lo;
}

__device__ __forceinline__ unsigned sort64_u32(unsigned v, int lane) {
#pragma unroll
  for (int k = 2; k <= 64; k <<= 1) {
#pragma unroll
    for (int j = k >> 1; j >= 1; j >>= 1) {
      unsigned ov = shflx(v, j);
      bool kmin = ((lane & j) == 0) == ((lane & k) == 0);
      v = kmin ? (v < ov ? v : ov) : (v > ov ? v : ov);
    }
  }
  return v;
}

__device__ __forceinline__ void sort128_u32(unsigned& a, unsigned& b, int lane) {
#pragma unroll
  for (int k = 2; k <= 128; k <<= 1) {
#pragma unroll
    for (int j = k >> 1; j >= 1; j >>= 1) {
      if (j == 64) {
        unsigned mn = a < b ? a : b, mx = a < b ? b : a;
        a = mn; b = mx;
      } else {
        unsigned oa = shflx(a, j), ob = shflx(b, j);
        bool lower = (lane & j) == 0;
        bool asca, ascb;
        if (k == 128) { asca = true; ascb = true; }
        else if (k == 64) { asca = true; ascb = false; }
        else { asca = ((lane & k) == 0); ascb = asca; }
        a = (lower == asca) ? (a < oa ? a : oa) : (a > oa ? a : oa);
        b = (lower == ascb) ? (b < ob ? b : ob) : (b > ob ? b : ob);
      }
    }
  }
}

__device__ __forceinline__ unsigned long long sort64_u64(unsigned long long v, int lane) {
#pragma unroll
  for (int k = 2; k <= 64; k <<= 1) {
#pragma unroll
    for (int j = k >> 1; j >= 1; j >>= 1) {
      unsigned long long ov = shflx64(v, j);
      bool kmin = ((lane & j) == 0) == ((lane & k) == 0);
      v = kmin ? (v < ov ? v : ov) : (v > ov ? v : ov);
    }
  }
  return v;
}

__device__ __forceinline__ void sort128_u64(unsigned long long& a, unsigned long long& b,
                                            int lane) {
#pragma unroll
  for (int k = 2; k <= 128; k <<= 1) {
#pragma unroll
    for (int j = k >> 1; j >= 1; j >>= 1) {
      if (j == 64) {
        unsigned long long mn = a < b ? a : b, mx = a < b ? b : a;
        a = mn; b = mx;
      } else {
        unsigned long long oa = shflx64(a, j), ob = shflx64(b, j);
        bool lower = (lane & j) == 0;
        bool asca, ascb;
        if (k == 128) { asca = true; ascb = true; }
        else if (k == 64) { asca = true; ascb = false; }
        else { asca = ((lane & k) == 0); ascb = asca; }
        a = (lower == asca) ? (a < oa ? a : oa) : (a > oa ? a : oa);
        b = (lower == ascb) ? (b < ob ? b : ob) : (b > ob ? b : ob);
      }
    }
  }
}

// ---------------- shared selection body ----------------
// MAP=0: reg j at thread tid holds global index j*256+tid
// MAP=1: reg j at thread tid holds global index (j>>2)*1024 + tid*4 + (j&3)
struct TopkShared {
  unsigned wv[80];
  unsigned ck[128];
  int      ci[128];
  int      cnt_s;
  int      selm[20];
  float    part[4 * 256];
  float    fcv[80];
  int      fcm[80];
};

template <int MAP>
__device__ __forceinline__ int tk_enc(int j, int tid) {
  if (MAP == 0) return j * 256 + tid;
  return ((j >> 2) << 10) | (tid << 2) | (j & 3);
}

template <int MAP>
__device__ __forceinline__ void topk_select(float v[16], TopkShared& sh,
                                            int tid, int lane, int wid) {
  float M = v[0];
#pragma unroll
  for (int j = 1; j < 16; ++j) M = fmaxf(M, v[j]);

  unsigned mk = sort64_u32(f2u(M), lane);

  if (tid == 0) sh.cnt_s = 0;
  if (lane >= 44) sh.wv[wid * 20 + (63 - lane)] = mk;
  __syncthreads();

  unsigned a0 = sh.wv[lane];
  unsigned b0 = (lane < 16) ? sh.wv[64 + lane] : 0u;
  sort128_u32(a0, b0, lane);
  unsigned T0k = (unsigned)__shfl((int)b0, 44);
  float T0f = u2f(T0k);

#pragma unroll
  for (int j = 0; j < 16; ++j) {
    bool pred = (v[j] >= T0f);
    unsigned long long m = __ballot(pred);
    int below = __popcll(m & ((1ull << lane) - 1ull));
    int cw = __popcll(m);
    int base = 0;
    if (lane == 0 && cw) base = atomicAdd(&sh.cnt_s, cw);
    base = __shfl(base, 0);
    if (pred) {
      int pos = base + below;
      if (pos < 128) { sh.ck[pos] = f2u(v[j]); sh.ci[pos] = tk_enc<MAP>(j, tid); }
    }
  }
  __syncthreads();
  const int cnt = sh.cnt_s;

  if (cnt <= 128) {
    // only wave 0 sorts (result used only from wave 0)
    if (wid == 0) {
      unsigned long long k0 = (lane < cnt)
          ? (((unsigned long long)sh.ck[lane] << 32) | (unsigned)(~sh.ci[lane])) : 0ull;
      if (cnt <= 64) {
        k0 = sort64_u64(k0, lane);
        if (lane >= 44) sh.selm[63 - lane] = (int)(~(unsigned)k0);
      } else {
        unsigned long long k1 = (64 + lane < cnt)
            ? (((unsigned long long)sh.ck[64 + lane] << 32) | (unsigned)(~sh.ci[64 + lane]))
            : 0ull;
        sort128_u64(k0, k1, lane);
        if (lane >= 44) sh.selm[63 - lane] = (int)(~(unsigned)k1);
      }
    }
  } else {
    // fallback: exact iterative extraction (ties / degenerate data)
    for (int it = 0; it < 20; ++it) {
      float bv = v[0]; int bj = 0;
#pragma unroll
      for (int j = 1; j < 16; ++j)
        if (v[j] > bv) { bv = v[j]; bj = j; }
      int bm = tk_enc<MAP>(bj, tid);
#pragma unroll
      for (int off = 1; off < 64; off <<= 1) {
        float ov = __shfl_xor(bv, off);
        int om = __shfl_xor(bm, off);
        if (ov > bv || (ov == bv && om < bm)) { bv = ov; bm = om; }
      }
      if (lane == 0) { sh.fcv[wid * 20 + it] = bv; sh.fcm[wid * 20 + it] = bm; }
      if (MAP == 0) {
        if ((bm & 255) == tid) v[bm >> 8] = -3.0e38f;
      } else {
        if (((bm >> 2) & 255) == tid) v[(((bm >> 10) & 3) << 2) | (bm & 3)] = -3.0e38f;
      }
    }
    __syncthreads();
    if (wid == 0) {
      float c0 = sh.fcv[lane]; int m0 = sh.fcm[lane];
      float c1 = (lane < 16) ? sh.fcv[64 + lane] : -3.0e38f;
      int   m1 = (lane < 16) ? sh.fcm[64 + lane] : 0x7fffffff;
      for (int it = 0; it < 20; ++it) {
        float bv; int bm, bs;
        if (c0 > c1 || (c0 == c1 && m0 < m1)) { bv = c0; bm = m0; bs = lane; }
        else { bv = c1; bm = m1; bs = 64 + lane; }
#pragma unroll
        for (int off = 1; off < 64; off <<= 1) {
          float ov = __shfl_xor(bv, off);
          int om = __shfl_xor(bm, off);
          int os = __shfl_xor(bs, off);
          if (ov > bv || (ov == bv && om < bm)) { bv = ov; bm = om; bs = os; }
        }
        if (lane == 0) sh.selm[it] = bm;
        if (bs == lane) c0 = -3.0e38f;
        else if (bs == 64 + lane) c1 = -3.0e38f;
      }
    }
  }
  __syncthreads();
}

__device__ __forceinline__ void topk_gather(const TopkShared& sh, TopkShared& shm,
                                            const float* __restrict__ P,
                                            const float* __restrict__ Q,
                                            float* __restrict__ Y, int ldy, int O,
                                            int bBase, int n, int tid, int lane, int wid) {
  for (int o = lane; o < O; o += 64) {
    float q = Q[(size_t)(bBase + n) * O + o];
    float best = -3.0e38f;
#pragma unroll
    for (int kk = 0; kk < 5; ++kk) {
      int s = sh.selm[wid * 5 + kk];
      float t = P[(size_t)(bBase + s) * O + o] + q;
      t = t > 0.f ? t : 0.2f * t;
      best = fmaxf(best, t);
    }
    shm.part[wid * 256 + o] = best;
  }
  __syncthreads();
  for (int o = tid; o < O; o += 256) {
    float b2 = fmaxf(fmaxf(shm.part[o], shm.part[256 + o]),
                     fmaxf(shm.part[512 + o], shm.part[768 + o]));
    Y[(size_t)(bBase + n) * ldy + o] = b2;
  }
}

// topk body on a row of a materialized D (MAP=1 vectorized reads)
__device__ __forceinline__ void topk_row_body(
    const float* __restrict__ drow, TopkShared& sh,
    const float* __restrict__ P, const float* __restrict__ Q,
    float* __restrict__ Y, int ldy, int O, int bBase, int n,
    int tid, int lane, int wid) {
  float v[16];
#pragma unroll
  for (int c = 0; c < 4; ++c) {
    float4 f = *(const float4*)&drow[c * 1024 + tid * 4];
    v[c * 4 + 0] = f.x; v[c * 4 + 1] = f.y;
    v[c * 4 + 2] = f.z; v[c * 4 + 3] = f.w;
  }
  topk_select<1>(v, sh, tid, lane, wid);
  topk_gather(sh, sh, P, Q, Y, ldy, O, bBase, n, tid, lane, wid);
}

// dist body: one 64x64 triangular tile (tile id t in [0,2080))
__device__ __forceinline__ void dist_tile_body(
    int t, const float* __restrict__ X, int lda, int C,
    const float* __restrict__ sq, float* __restrict__ D,
    float As[16][68], float Bs[16][68], int tid) {
  int bi = 0;
  while (t >= 64 - bi) { t -= 64 - bi; ++bi; }
  const int bj = bi + t;
  const int row0 = bi * 64, col0 = bj * 64;
  const int tx = tid & 15, ty = tid >> 4;

  const int lr = tid >> 2;
  const int lc = (tid & 3) << 2;
  const float* Ap = X + (size_t)(row0 + lr) * lda + lc;
  const float* Bp = X + (size_t)(col0 + lr) * lda + lc;

  float acc[4][4] = {};
  for (int c0 = 0; c0 < C; c0 += 16) {
    float4 av = *(const float4*)(Ap + c0);
    float4 bv = *(const float4*)(Bp + c0);
    As[lc + 0][lr] = av.x; As[lc + 1][lr] = av.y;
    As[lc + 2][lr] = av.z; As[lc + 3][lr] = av.w;
    Bs[lc + 0][lr] = bv.x; Bs[lc + 1][lr] = bv.y;
    Bs[lc + 2][lr] = bv.z; Bs[lc + 3][lr] = bv.w;
    __syncthreads();
#pragma unroll
    for (int c = 0; c < 16; ++c) {
      float4 a4 = *(const float4*)(&As[c][ty << 2]);
      float4 b4 = *(const float4*)(&Bs[c][tx << 2]);
      float aa[4] = {a4.x, a4.y, a4.z, a4.w};
      float bb[4] = {b4.x, b4.y, b4.z, b4.w};
#pragma unroll
      for (int i = 0; i < 4; ++i)
#pragma unroll
        for (int j = 0; j < 4; ++j) acc[i][j] = fmaf(aa[i], bb[j], acc[i][j]);
    }
    __syncthreads();
  }

  float rs[4], cs[4];
#pragma unroll
  for (int i = 0; i < 4; ++i) rs[i] = sq[row0 + (ty << 2) + i];
#pragma unroll
  for (int j = 0; j < 4; ++j) cs[j] = sq[col0 + (tx << 2) + j];

#pragma unroll
  for (int i = 0; i < 4; ++i) {
    const int row = row0 + (ty << 2) + i;
    float vals[4];
#pragma unroll
    for (int j = 0; j < 4; ++j) vals[j] = (2.0f * acc[i][j] - rs[i]) - cs[j];
    *(float4*)&D[(size_t)row * NPTS + col0 + (tx << 2)] =
        make_float4(vals[0], vals[1], vals[2], vals[3]);
  }

  if (bi != bj) {
#pragma unroll
    for (int j = 0; j < 4; ++j) {
      const int col = col0 + (tx << 2) + j;
      float mv[4];
#pragma unroll
      for (int i = 0; i < 4; ++i) mv[i] = (2.0f * acc[i][j] - cs[j]) - rs[i];
      *(float4*)&D[(size_t)col * NPTS + row0 + (ty << 2)] =
          make_float4(mv[0], mv[1], mv[2], mv[3]);
    }
  }
}

// ---------------- fold kernels ----------------
__global__ void fold_edge_k(const float* __restrict__ w, const float* __restrict__ g,
                            const float* __restrict__ bt, const float* __restrict__ m,
                            const float* __restrict__ v, int O, int C,
                            float* __restrict__ wdf, float* __restrict__ wqf,
                            float* __restrict__ c0) {
  int t = blockIdx.x * 256 + threadIdx.x;
  if (t >= O * C) return;
  int o = t / C, c = t - o * C;
  float A = g[o] * (1.0f / sqrtf(v[o] + EPSF));
  float wd = w[o * 2 * C + c], wc = w[o * 2 * C + C + c];
  wdf[t] = A * wd;
  wqf[t] = A * (wc - wd);
  if (c == 0) c0[o] = bt[o] - m[o] * A;
}

__global__ void fold_head_k(const float* __restrict__ hw, const float* __restrict__ hb,
                            const float* __restrict__ hg, const float* __restrict__ hbt,
                            const float* __restrict__ hm, const float* __restrict__ hv,
                            int O, int C, float* __restrict__ hwf, float* __restrict__ cb) {
  int t = blockIdx.x * 256 + threadIdx.x;
  if (t >= O * C) return;
  int o = t / C, c = t - o * C;
  float A = hg[o] * (1.0f / sqrtf(hv[o] + EPSF));
  hwf[t] = A * hw[t];
  if (c == 0) cb[o] = (hb[o] - hm[o]) * A + hbt[o];
}

// ---------------- squared norms ----------------
__global__ void sq_k(const float* __restrict__ X, int lda, int C,
                     float* __restrict__ sq, int nrows) {
  int r = blockIdx.x * 256 + threadIdx.x;
  if (r >= nrows) return;
  const float* p = X + (size_t)r * lda;
  float s = 0.f;
  for (int c = 0; c < C; ++c) s += p[c] * p[c];
  sq[r] = s;
}

// ---------------- layer-1 (C=3) kernels ----------------
__global__ void pq3_k(const float* __restrict__ x, const float* __restrict__ wdf,
                      const float* __restrict__ wqf, const float* __restrict__ c0,
                      float* __restrict__ P, float* __restrict__ Q) {
  int t = blockIdx.x * 256 + threadIdx.x;
  int r = t >> 6, o = t & 63;
  float x0 = x[r * 3], x1 = x[r * 3 + 1], x2 = x[r * 3 + 2];
  P[(size_t)r * 64 + o] = x0 * wdf[o * 3] + x1 * wdf[o * 3 + 1] + x2 * wdf[o * 3 + 2];
  Q[(size_t)r * 64 + o] = x0 * wqf[o * 3] + x1 * wqf[o * 3 + 1] + x2 * wqf[o * 3 + 2] + c0[o];
}

// ---------------- fused L1 top-k (C=3 inline distances, MAP=0) ----------------
__global__ __launch_bounds__(256) void topk_l1_fused(
    const float* __restrict__ x, const float* __restrict__ sqg,
    const float* __restrict__ P, const float* __restrict__ Q,
    float* __restrict__ Y, int ldy) {
  const int tid = threadIdx.x;
  const int lane = tid & 63, wid = tid >> 6;
  const int n = blockIdx.x;
  const int bBase = blockIdx.y * NPTS;
  const float* xb = x + (size_t)bBase * 3;
  const float* sqb = sqg + bBase;

  __shared__ TopkShared sh;

  float xn0 = xb[n * 3], xn1 = xb[n * 3 + 1], xn2 = xb[n * 3 + 2];
  float sn = sqb[n];
  float v[16];
#pragma unroll
  for (int j = 0; j < 16; ++j) {
    int mc = j * 256 + tid;
    float y0 = xb[mc * 3], y1 = xb[mc * 3 + 1], y2 = xb[mc * 3 + 2];
    float inner = xn0 * y0 + xn1 * y1 + xn2 * y2;
    v[j] = 2.0f * inner - sn - sqb[mc];
  }

  topk_select<0>(v, sh, tid, lane, wid);
  topk_gather(sh, sh, P, Q, Y, ldy, 64, bBase, n, tid, lane, wid);
}

// ---------------- standalone dist (batch via blockIdx.y) ----------------
__global__ __launch_bounds__(256) void dist_sym64_k(
    const float* __restrict__ X0, int lda, int C,
    const float* __restrict__ sq0, float* __restrict__ D0) {
  const int b = blockIdx.y;
  __shared__ __align__(16) float As[16][68];
  __shared__ __align__(16) float Bs[16][68];
  dist_tile_body(blockIdx.x, X0 + (size_t)b * NPTS * lda, lda, C,
                 sq0 + (size_t)b * NPTS, D0 + (size_t)b * NPTS * NPTS,
                 As, Bs, threadIdx.x);
}

// ---------------- fused: dist(batch B1 ptrs) + topk(batch B0 ptrs) ----------------
// blocks [0,2080) do dist tiles on (X1,sq1,D1); blocks [2080, 2080+4096) do
// topk rows on (D0,P,Q->Y) with row base bBase0. Disjoint data => no ordering
// hazard; per-block branch is uniform.
__global__ __launch_bounds__(256) void dist_topk_fused(
    const float* __restrict__ X1, int lda, int C,
    const float* __restrict__ sq1, float* __restrict__ D1,
    const float* __restrict__ D0,
    const float* __restrict__ P, const float* __restrict__ Q,
    float* __restrict__ Y, int ldy, int O, int bBase0) {
  __shared__ union {
    struct { float As[16][68]; float Bs[16][68]; } g;
    TopkShared t;
  } u;
  const int tid = threadIdx.x;
  if (blockIdx.x < 2080) {
    dist_tile_body(blockIdx.x, X1, lda, C, sq1, D1, u.g.As, u.g.Bs, tid);
  } else {
    const int n = blockIdx.x - 2080;
    const int lane = tid & 63, wid = tid >> 6;
    topk_row_body(D0 + (size_t)n * NPTS, u.t, P, Q, Y, ldy, O, bBase0, n,
                  tid, lane, wid);
  }
}

// ---------------- fused P/Q GEMM: P = A@Wd^T, Q = A@Wq^T + c0 ----------------
__global__ __launch_bounds__(256) void gemm_pq(
    const float* __restrict__ A, int lda,
    const float* __restrict__ Wd, const float* __restrict__ Wq, int ldb,
    float* __restrict__ P, float* __restrict__ Q, int ldo, int C,
    const float* __restrict__ c0b) {
  __shared__ __align__(16) float As[16][68];
  __shared__ __align__(16) float Bd[16][68];
  __shared__ __align__(16) float Bq[16][68];
  const int tx = threadIdx.x, ty = threadIdx.y;
  const int tid = ty * 16 + tx;
  const int row0 = blockIdx.y * 64, col0 = blockIdx.x * 64;
  const int lr = tid >> 2;
  const int lc = (tid & 3) << 2;
  const float* Ap = A + (size_t)(row0 + lr) * lda + lc;
  const float* Dp = Wd + (size_t)(col0 + lr) * ldb + lc;
  const float* Qp = Wq + (size_t)(col0 + lr) * ldb + lc;
  float accp[4][4] = {};
  float accq[4][4] = {};
  for (int c0 = 0; c0 < C; c0 += 16) {
    float4 av = *(const float4*)(Ap + c0);
    float4 dv = *(const float4*)(Dp + c0);
    float4 qv = *(const float4*)(Qp + c0);
    As[lc + 0][lr] = av.x; As[lc + 1][lr] = av.y;
    As[lc + 2][lr] = av.z; As[lc + 3][lr] = av.w;
    Bd[lc + 0][lr] = dv.x; Bd[lc + 1][lr] = dv.y;
    Bd[lc + 2][lr] = dv.z; Bd[lc + 3][lr] = dv.w;
    Bq[lc + 0][lr] = qv.x; Bq[lc + 1][lr] = qv.y;
    Bq[lc + 2][lr] = qv.z; Bq[lc + 3][lr] = qv.w;
    __syncthreads();
#pragma unroll
    for (int c = 0; c < 16; ++c) {
      float4 a4 = *(const float4*)(&As[c][ty << 2]);
      float4 d4 = *(const float4*)(&Bd[c][tx << 2]);
      float4 q4 = *(const float4*)(&Bq[c][tx << 2]);
      float aa[4] = {a4.x, a4.y, a4.z, a4.w};
      float dd[4] = {d4.x, d4.y, d4.z, d4.w};
      float qq[4] = {q4.x, q4.y, q4.z, q4.w};
#pragma unroll
      for (int i = 0; i < 4; ++i)
#pragma unroll
        for (int j = 0; j < 4; ++j) {
          accp[i][j] = fmaf(aa[i], dd[j], accp[i][j]);
          accq[i][j] = fmaf(aa[i], qq[j], accq[i][j]);
        }
    }
    __syncthreads();
  }
  const int row = row0 + (ty << 2), col = col0 + (tx << 2);
#pragma unroll
  for (int i = 0; i < 4; ++i) {
    *(float4*)(&P[(size_t)(row + i) * ldo + col]) = make_float4(
        accp[i][0], accp[i][1], accp[i][2], accp[i][3]);
    *(float4*)(&Q[(size_t)(row + i) * ldo + col]) = make_float4(
        accq[i][0] + c0b[col + 0], accq[i][1] + c0b[col + 1],
        accq[i][2] + c0b[col + 2], accq[i][3] + c0b[col + 3]);
  }
}

// ---------------- generic fp32 GEMM (dist fallback / head) ----------------
template <int EPI>
__global__ __launch_bounds__(256) void gemm_nt(
    const float* __restrict__ A, int lda,
    const float* __restrict__ Bm, int ldb,
    float* __restrict__ Out, int ldo, int C,
    const float* __restrict__ sqA, const float* __restrict__ sqB,
    const float* __restrict__ bias) {
  __shared__ __align__(16) float As[16][68];
  __shared__ __align__(16) float Bs[16][68];
  const int tx = threadIdx.x, ty = threadIdx.y;
  const int tid = ty * 16 + tx;
  const int row0 = blockIdx.y * 64, col0 = blockIdx.x * 64;
  const int lr = tid >> 2;
  const int lc = (tid & 3) << 2;
  const float* Ap = A + (size_t)(row0 + lr) * lda + lc;
  const float* Bp = Bm + (size_t)(col0 + lr) * ldb + lc;
  float acc[4][4] = {};
  for (int c0 = 0; c0 < C; c0 += 16) {
    float4 av = *(const float4*)(Ap + c0);
    float4 bv = *(const float4*)(Bp + c0);
    As[lc + 0][lr] = av.x; As[lc + 1][lr] = av.y;
    As[lc + 2][lr] = av.z; As[lc + 3][lr] = av.w;
    Bs[lc + 0][lr] = bv.x; Bs[lc + 1][lr] = bv.y;
    Bs[lc + 2][lr] = bv.z; Bs[lc + 3][lr] = bv.w;
    __syncthreads();
#pragma unroll
    for (int c = 0; c < 16; ++c) {
      float4 a4 = *(const float4*)(&As[c][ty << 2]);
      float4 b4 = *(const float4*)(&Bs[c][tx << 2]);
      float aa[4] = {a4.x, a4.y, a4.z, a4.w};
      float bb[4] = {b4.x, b4.y, b4.z, b4.w};
#pragma unroll
      for (int i = 0; i < 4; ++i)
#pragma unroll
        for (int j = 0; j < 4; ++j) acc[i][j] = fmaf(aa[i], bb[j], acc[i][j]);
    }
    __syncthreads();
  }
  const int row = row0 + (ty << 2), col = col0 + (tx << 2);
#pragma unroll
  for (int i = 0; i < 4; ++i) {
    float vals[4];
#pragma unroll
    for (int j = 0; j < 4; ++j) {
      float va = acc[i][j];
      if (EPI == 0) vals[j] = va;
      else if (EPI == 1) vals[j] = va + bias[col + j];
      else if (EPI == 2) vals[j] = 2.0f * va - sqA[row + i] - sqB[col + j];
      else { float t = va + bias[col + j]; vals[j] = t > 0.f ? t : 0.f; }
    }
    *(float4*)(&Out[(size_t)(row + i) * ldo + col]) =
        make_float4(vals[0], vals[1], vals[2], vals[3]);
  }
}

// ---------------- standalone top-20 from materialized D ----------------
__global__ __launch_bounds__(256) void topk_max_f32(
    const float* __restrict__ D, long long dStride,
    const float* __restrict__ P, const float* __restrict__ Q,
    float* __restrict__ Y, int ldy, int O, int bBase0, int r0) {
  const int tid = threadIdx.x;
  const int lane = tid & 63, wid = tid >> 6;
  const int nloc = blockIdx.x;
  const int n = r0 + nloc;
  const int bBase = bBase0 + blockIdx.y * NPTS;
  const float* drow = D + (size_t)blockIdx.y * (size_t)dStride + (size_t)nloc * NPTS;
  __shared__ TopkShared sh;
  topk_row_body(drow, sh, P, Q, Y, ldy, O, bBase, n, tid, lane, wid);
}

// ---------------- final 128->1 dot ----------------
__global__ void final_dot_k(const float* __restrict__ h2, const float* __restrict__ w3,
                            const float* __restrict__ b3, float* __restrict__ out) {
  int gt = blockIdx.x * 256 + threadIdx.x;
  int row = gt >> 6, lane = gt & 63;
  float s = h2[(size_t)row * 128 + lane] * w3[lane] +
            h2[(size_t)row * 128 + 64 + lane] * w3[64 + lane];
#pragma unroll
  for (int off = 32; off > 0; off >>= 1) s += __shfl_down(s, off);
  if (lane == 0) out[row] = s + b3[0];
}

extern "C" void kernel_launch(void* const* d_in, const int* in_sizes, int n_in,
                              void* d_out, int out_size, void* d_ws, size_t ws_size,
                              hipStream_t stream) {
  const int B = 2, N = NPTS;
  const size_t NN = (size_t)N * N;
  const float* x = (const float*)d_in[0];
  const float* w[4]  = {(const float*)d_in[1], (const float*)d_in[6],
                        (const float*)d_in[11], (const float*)d_in[16]};
  const float* g[4]  = {(const float*)d_in[2], (const float*)d_in[7],
                        (const float*)d_in[12], (const float*)d_in[17]};
  const float* bt[4] = {(const float*)d_in[3], (const float*)d_in[8],
                        (const float*)d_in[13], (const float*)d_in[18]};
  const float* mm[4] = {(const float*)d_in[4], (const float*)d_in[9],
                        (const float*)d_in[14], (const float*)d_in[19]};
  const float* vv[4] = {(const float*)d_in[5], (const float*)d_in[10],
                        (const float*)d_in[15], (const float*)d_in[20]};
  const float* hw1 = (const float*)d_in[21]; const float* hb1 = (const float*)d_in[22];
  const float* hg1 = (const float*)d_in[23]; const float* hbt1 = (const float*)d_in[24];
  const float* hm1 = (const float*)d_in[25]; const float* hv1 = (const float*)d_in[26];
  const float* hw2 = (const float*)d_in[27]; const float* hb2 = (const float*)d_in[28];
  const float* hg2 = (const float*)d_in[29]; const float* hbt2 = (const float*)d_in[30];
  const float* hm2 = (const float*)d_in[31]; const float* hv2 = (const float*)d_in[32];
  const float* hw3 = (const float*)d_in[33]; const float* hb3 = (const float*)d_in[34];
  float* out = (float*)d_out;

  char* wsb = (char*)d_ws;
  size_t off = 0;
  auto alloc = [&](size_t nbytes) {
    char* p = wsb + off;
    off += (nbytes + 255) & ~(size_t)255;
    return p;
  };
  float* xc   = (float*)alloc((size_t)B * N * 512 * 4);
  float* P    = (float*)alloc((size_t)B * N * 256 * 4);
  float* Q    = (float*)alloc((size_t)B * N * 256 * 4);
  float* sq   = (float*)alloc((size_t)B * N * 4);
  float* wdf  = (float*)alloc(256 * 256 * 4);
  float* wqf  = (float*)alloc(256 * 256 * 4);
  float* c0   = (float*)alloc(256 * 4);
  float* hwf1 = (float*)alloc(256 * 512 * 4);
  float* cb1  = (float*)alloc(256 * 4);
  float* hwf2 = (float*)alloc(128 * 256 * 4);
  float* cb2  = (float*)alloc(128 * 4);
  float* D    = (float*)(wsb + off);
  size_t avail = (ws_size > off) ? (ws_size - off) : 0;
  const bool merged = (avail >= (size_t)B * NN * 4);
  int rows_tile = 4096;
  if (!merged)
    while ((size_t)rows_tile * N * 4 > avail && rows_tile > 64) rows_tile >>= 1;

  // dims = [(3,64), (64,64), (64,128), (128,256)]
  const int Cin[4]  = {3, 64, 64, 128};
  const int Oc[4]   = {64, 64, 128, 256};
  const int ioff[4] = {0, 0, 64, 128};
  const int ooff[4] = {0, 64, 128, 256};
  dim3 blk2(16, 16);

  for (int L = 0; L < 4; ++L) {
    const int C = Cin[L], O = Oc[L];
    const float* in = (L == 0) ? x : (xc + ioff[L]);
    const int lda = (L == 0) ? 3 : 512;

    fold_edge_k<<<dim3((O * C + 255) / 256), dim3(256), 0, stream>>>(
        w[L], g[L], bt[L], mm[L], vv[L], O, C, wdf, wqf, c0);
    sq_k<<<dim3((B * N + 255) / 256), dim3(256), 0, stream>>>(in, lda, C, sq, B * N);
    if (L == 0) {
      pq3_k<<<dim3(B * N * 64 / 256), dim3(256), 0, stream>>>(x, wdf, wqf, c0, P, Q);
    } else {
      gemm_pq<<<dim3(O / 64, B * N / 64), blk2, 0, stream>>>(
          in, lda, wdf, wqf, C, P, Q, O, C, c0);
    }

    if (L == 0) {
      topk_l1_fused<<<dim3(N, B), dim3(256), 0, stream>>>(
          x, sq, P, Q, xc + ooff[0], 512);
      continue;
    }
    if (merged) {
      // software pipeline: dist(b0); [dist(b1) || topk(b0)]; topk(b1)
      dist_sym64_k<<<dim3(2080, 1), dim3(256), 0, stream>>>(in, lda, C, sq, D);
      dist_topk_fused<<<dim3(2080 + 4096), dim3(256), 0, stream>>>(
          in + (size_t)N * lda, lda, C, sq + N, D + NN,
          D, P, Q, xc + ooff[L], 512, O, 0);
      topk_max_f32<<<dim3(N, 1), dim3(256), 0, stream>>>(
          D + NN, 0, P, Q, xc + ooff[L], 512, O, N, 0);
      continue;
    }
    for (int b = 0; b < B; ++b) {
      for (int r0 = 0; r0 < N; r0 += rows_tile) {
        gemm_nt<2><<<dim3(N / 64, rows_tile / 64), blk2, 0, stream>>>(
            in + ((size_t)b * N + r0) * lda, lda, in + (size_t)b * N * lda, lda,
            D, N, C, sq + b * N + r0, sq + b * N, nullptr);
        topk_max_f32<<<dim3(rows_tile, 1), dim3(256), 0, stream>>>(
            D, 0, P, Q, xc + ooff[L], 512, O, b * N, r0);
      }
    }
  }

  fold_head_k<<<dim3((256 * 512 + 255) / 256), dim3(256), 0, stream>>>(
      hw1, hb1, hg1, hbt1, hm1, hv1, 256, 512, hwf1, cb1);
  fold_head_k<<<dim3((128 * 256 + 255) / 256), dim3(256), 0, stream>>>(
      hw2, hb2, hg2, hbt2, hm2, hv2, 128, 256, hwf2, cb2);

  float* h1 = P;
  float* h2 = Q;
  gemm_nt<3><<<dim3(256 / 64, B * N / 64), blk2, 0, stream>>>(
      xc, 512, hwf1, 512, h1, 256, 512, nullptr, nullptr, cb1);
  gemm_nt<3><<<dim3(128 / 64, B * N / 64), blk2, 0, stream>>>(
      h1, 256, hwf2, 256, h2, 128, 256, nullptr, nullptr, cb2);
  final_dot_k<<<dim3(B * N / 4), dim3(256), 0, stream>>>(h2, hw3, hb3, out);
}

// Round 19
// 598.729 us; speedup vs baseline: 1.1106x; 1.1106x over previous
//
#include <hip/hip_runtime.h>

#define NPTS 4096
#define EPSF 1e-5f

// ---------------- sortable-key helpers ----------------
__device__ __forceinline__ unsigned f2u(float f) {
  unsigned b = __float_as_uint(f);
  return (b & 0x80000000u) ? ~b : (b | 0x80000000u);
}
__device__ __forceinline__ float u2f(unsigned u) {
  unsigned b = (u & 0x80000000u) ? (u & 0x7fffffffu) : ~u;
  return __uint_as_float(b);
}
__device__ __forceinline__ unsigned shflx(unsigned v, int j) {
  return (unsigned)__shfl_xor((int)v, j);
}
__device__ __forceinline__ unsigned long long shflx64(unsigned long long v, int j) {
  unsigned lo = (unsigned)__shfl_xor((int)(unsigned)(v & 0xffffffffull), j);
  unsigned hi = (unsigned)__shfl_xor((int)(unsigned)(v >> 32), j);
  return ((unsigned long long)hi << 32) | lo;
}

__device__ __forceinline__ unsigned sort64_u32(unsigned v, int lane) {
#pragma unroll
  for (int k = 2; k <= 64; k <<= 1) {
#pragma unroll
    for (int j = k >> 1; j >= 1; j >>= 1) {
      unsigned ov = shflx(v, j);
      bool kmin = ((lane & j) == 0) == ((lane & k) == 0);
      v = kmin ? (v < ov ? v : ov) : (v > ov ? v : ov);
    }
  }
  return v;
}

__device__ __forceinline__ void sort128_u32(unsigned& a, unsigned& b, int lane) {
#pragma unroll
  for (int k = 2; k <= 128; k <<= 1) {
#pragma unroll
    for (int j = k >> 1; j >= 1; j >>= 1) {
      if (j == 64) {
        unsigned mn = a < b ? a : b, mx = a < b ? b : a;
        a = mn; b = mx;
      } else {
        unsigned oa = shflx(a, j), ob = shflx(b, j);
        bool lower = (lane & j) == 0;
        bool asca, ascb;
        if (k == 128) { asca = true; ascb = true; }
        else if (k == 64) { asca = true; ascb = false; }
        else { asca = ((lane & k) == 0); ascb = asca; }
        a = (lower == asca) ? (a < oa ? a : oa) : (a > oa ? a : oa);
        b = (lower == ascb) ? (b < ob ? b : ob) : (b > ob ? b : ob);
      }
    }
  }
}

__device__ __forceinline__ unsigned long long sort64_u64(unsigned long long v, int lane) {
#pragma unroll
  for (int k = 2; k <= 64; k <<= 1) {
#pragma unroll
    for (int j = k >> 1; j >= 1; j >>= 1) {
      unsigned long long ov = shflx64(v, j);
      bool kmin = ((lane & j) == 0) == ((lane & k) == 0);
      v = kmin ? (v < ov ? v : ov) : (v > ov ? v : ov);
    }
  }
  return v;
}

__device__ __forceinline__ void sort128_u64(unsigned long long& a, unsigned long long& b,
                                            int lane) {
#pragma unroll
  for (int k = 2; k <= 128; k <<= 1) {
#pragma unroll
    for (int j = k >> 1; j >= 1; j >>= 1) {
      if (j == 64) {
        unsigned long long mn = a < b ? a : b, mx = a < b ? b : a;
        a = mn; b = mx;
      } else {
        unsigned long long oa = shflx64(a, j), ob = shflx64(b, j);
        bool lower = (lane & j) == 0;
        bool asca, ascb;
        if (k == 128) { asca = true; ascb = true; }
        else if (k == 64) { asca = true; ascb = false; }
        else { asca = ((lane & k) == 0); ascb = asca; }
        a = (lower == asca) ? (a < oa ? a : oa) : (a > oa ? a : oa);
        b = (lower == ascb) ? (b < ob ? b : ob) : (b > ob ? b : ob);
      }
    }
  }
}

// ---------------- shared selection body ----------------
// MAP=0: reg j at thread tid holds global index j*256+tid
// MAP=1: reg j at thread tid holds global index (j>>2)*1024 + tid*4 + (j&3)
struct TopkShared {
  unsigned wv[80];
  unsigned ck[128];
  int      ci[128];
  int      cnt_s;
  int      selm[20];
  float    part[4 * 256];
  float    fcv[80];
  int      fcm[80];
  int      sblk[64];
  int      nsel;
  unsigned tkey;
};

template <int MAP>
__device__ __forceinline__ int tk_enc(int j, int tid) {
  if (MAP == 0) return j * 256 + tid;
  return ((j >> 2) << 10) | (tid << 2) | (j & 3);
}

template <int MAP>
__device__ __forceinline__ void topk_select(float v[16], TopkShared& sh,
                                            int tid, int lane, int wid) {
  float M = v[0];
#pragma unroll
  for (int j = 1; j < 16; ++j) M = fmaxf(M, v[j]);

  unsigned mk = sort64_u32(f2u(M), lane);

  if (tid == 0) sh.cnt_s = 0;
  if (lane >= 44) sh.wv[wid * 20 + (63 - lane)] = mk;
  __syncthreads();

  unsigned a0 = sh.wv[lane];
  unsigned b0 = (lane < 16) ? sh.wv[64 + lane] : 0u;
  sort128_u32(a0, b0, lane);
  unsigned T0k = (unsigned)__shfl((int)b0, 44);
  float T0f = u2f(T0k);

#pragma unroll
  for (int j = 0; j < 16; ++j) {
    bool pred = (v[j] >= T0f);
    unsigned long long m = __ballot(pred);
    int below = __popcll(m & ((1ull << lane) - 1ull));
    int cw = __popcll(m);
    int base = 0;
    if (lane == 0 && cw) base = atomicAdd(&sh.cnt_s, cw);
    base = __shfl(base, 0);
    if (pred) {
      int pos = base + below;
      if (pos < 128) { sh.ck[pos] = f2u(v[j]); sh.ci[pos] = tk_enc<MAP>(j, tid); }
    }
  }
  __syncthreads();
  const int cnt = sh.cnt_s;

  if (cnt <= 128) {
    if (wid == 0) {
      unsigned long long k0 = (lane < cnt)
          ? (((unsigned long long)sh.ck[lane] << 32) | (unsigned)(~sh.ci[lane])) : 0ull;
      if (cnt <= 64) {
        k0 = sort64_u64(k0, lane);
        if (lane >= 44) sh.selm[63 - lane] = (int)(~(unsigned)k0);
      } else {
        unsigned long long k1 = (64 + lane < cnt)
            ? (((unsigned long long)sh.ck[64 + lane] << 32) | (unsigned)(~sh.ci[64 + lane]))
            : 0ull;
        sort128_u64(k0, k1, lane);
        if (lane >= 44) sh.selm[63 - lane] = (int)(~(unsigned)k1);
      }
    }
  } else {
    // fallback: exact iterative extraction (ties / degenerate data)
    for (int it = 0; it < 20; ++it) {
      float bv = v[0]; int bj = 0;
#pragma unroll
      for (int j = 1; j < 16; ++j)
        if (v[j] > bv) { bv = v[j]; bj = j; }
      int bm = tk_enc<MAP>(bj, tid);
#pragma unroll
      for (int off = 1; off < 64; off <<= 1) {
        float ov = __shfl_xor(bv, off);
        int om = __shfl_xor(bm, off);
        if (ov > bv || (ov == bv && om < bm)) { bv = ov; bm = om; }
      }
      if (lane == 0) { sh.fcv[wid * 20 + it] = bv; sh.fcm[wid * 20 + it] = bm; }
      if (MAP == 0) {
        if ((bm & 255) == tid) v[bm >> 8] = -3.0e38f;
      } else {
        if (((bm >> 2) & 255) == tid) v[(((bm >> 10) & 3) << 2) | (bm & 3)] = -3.0e38f;
      }
    }
    __syncthreads();
    if (wid == 0) {
      float c0 = sh.fcv[lane]; int m0 = sh.fcm[lane];
      float c1 = (lane < 16) ? sh.fcv[64 + lane] : -3.0e38f;
      int   m1 = (lane < 16) ? sh.fcm[64 + lane] : 0x7fffffff;
      for (int it = 0; it < 20; ++it) {
        float bv; int bm, bs;
        if (c0 > c1 || (c0 == c1 && m0 < m1)) { bv = c0; bm = m0; bs = lane; }
        else { bv = c1; bm = m1; bs = 64 + lane; }
#pragma unroll
        for (int off = 1; off < 64; off <<= 1) {
          float ov = __shfl_xor(bv, off);
          int om = __shfl_xor(bm, off);
          int os = __shfl_xor(bs, off);
          if (ov > bv || (ov == bv && om < bm)) { bv = ov; bm = om; bs = os; }
        }
        if (lane == 0) sh.selm[it] = bm;
        if (bs == lane) c0 = -3.0e38f;
        else if (bs == 64 + lane) c1 = -3.0e38f;
      }
    }
  }
  __syncthreads();
}

__device__ __forceinline__ void topk_gather(const TopkShared& sh, TopkShared& shm,
                                            const float* __restrict__ P,
                                            const float* __restrict__ Q,
                                            float* __restrict__ Y, int ldy, int O,
                                            int bBase, int n, int tid, int lane, int wid) {
  for (int o = lane; o < O; o += 64) {
    float q = Q[(size_t)(bBase + n) * O + o];
    float best = -3.0e38f;
#pragma unroll
    for (int kk = 0; kk < 5; ++kk) {
      int s = sh.selm[wid * 5 + kk];
      float t = P[(size_t)(bBase + s) * O + o] + q;
      t = t > 0.f ? t : 0.2f * t;
      best = fmaxf(best, t);
    }
    shm.part[wid * 256 + o] = best;
  }
  __syncthreads();
  for (int o = tid; o < O; o += 256) {
    float b2 = fmaxf(fmaxf(shm.part[o], shm.part[256 + o]),
                     fmaxf(shm.part[512 + o], shm.part[768 + o]));
    Y[(size_t)(bBase + n) * ldy + o] = b2;
  }
}

// ---------------- fold kernels ----------------
__global__ void fold_edge_k(const float* __restrict__ w, const float* __restrict__ g,
                            const float* __restrict__ bt, const float* __restrict__ m,
                            const float* __restrict__ v, int O, int C,
                            float* __restrict__ wdf, float* __restrict__ wqf,
                            float* __restrict__ c0) {
  int t = blockIdx.x * 256 + threadIdx.x;
  if (t >= O * C) return;
  int o = t / C, c = t - o * C;
  float A = g[o] * (1.0f / sqrtf(v[o] + EPSF));
  float wd = w[o * 2 * C + c], wc = w[o * 2 * C + C + c];
  wdf[t] = A * wd;
  wqf[t] = A * (wc - wd);
  if (c == 0) c0[o] = bt[o] - m[o] * A;
}

__global__ void fold_head_k(const float* __restrict__ hw, const float* __restrict__ hb,
                            const float* __restrict__ hg, const float* __restrict__ hbt,
                            const float* __restrict__ hm, const float* __restrict__ hv,
                            int O, int C, float* __restrict__ hwf, float* __restrict__ cb) {
  int t = blockIdx.x * 256 + threadIdx.x;
  if (t >= O * C) return;
  int o = t / C, c = t - o * C;
  float A = hg[o] * (1.0f / sqrtf(hv[o] + EPSF));
  hwf[t] = A * hw[t];
  if (c == 0) cb[o] = (hb[o] - hm[o]) * A + hbt[o];
}

// ---------------- squared norms ----------------
__global__ void sq_k(const float* __restrict__ X, int lda, int C,
                     float* __restrict__ sq, int nrows) {
  int r = blockIdx.x * 256 + threadIdx.x;
  if (r >= nrows) return;
  const float* p = X + (size_t)r * lda;
  float s = 0.f;
  for (int c = 0; c < C; ++c) s += p[c] * p[c];
  sq[r] = s;
}

// ---------------- layer-1 (C=3) kernels ----------------
__global__ void pq3_k(const float* __restrict__ x, const float* __restrict__ wdf,
                      const float* __restrict__ wqf, const float* __restrict__ c0,
                      float* __restrict__ P, float* __restrict__ Q) {
  int t = blockIdx.x * 256 + threadIdx.x;
  int r = t >> 6, o = t & 63;
  float x0 = x[r * 3], x1 = x[r * 3 + 1], x2 = x[r * 3 + 2];
  P[(size_t)r * 64 + o] = x0 * wdf[o * 3] + x1 * wdf[o * 3 + 1] + x2 * wdf[o * 3 + 2];
  Q[(size_t)r * 64 + o] = x0 * wqf[o * 3] + x1 * wqf[o * 3 + 1] + x2 * wqf[o * 3 + 2] + c0[o];
}

// ---------------- fused L1 top-k (C=3 inline distances, MAP=0) ----------------
__global__ __launch_bounds__(256) void topk_l1_fused(
    const float* __restrict__ x, const float* __restrict__ sqg,
    const float* __restrict__ P, const float* __restrict__ Q,
    float* __restrict__ Y, int ldy) {
  const int tid = threadIdx.x;
  const int lane = tid & 63, wid = tid >> 6;
  const int n = blockIdx.x;
  const int bBase = blockIdx.y * NPTS;
  const float* xb = x + (size_t)bBase * 3;
  const float* sqb = sqg + bBase;

  __shared__ TopkShared sh;

  float xn0 = xb[n * 3], xn1 = xb[n * 3 + 1], xn2 = xb[n * 3 + 2];
  float sn = sqb[n];
  float v[16];
#pragma unroll
  for (int j = 0; j < 16; ++j) {
    int mc = j * 256 + tid;
    float y0 = xb[mc * 3], y1 = xb[mc * 3 + 1], y2 = xb[mc * 3 + 2];
    float inner = xn0 * y0 + xn1 * y1 + xn2 * y2;
    v[j] = 2.0f * inner - sn - sqb[mc];
  }

  topk_select<0>(v, sh, tid, lane, wid);
  topk_gather(sh, sh, P, Q, Y, ldy, 64, bBase, n, tid, lane, wid);
}

// ---------------- symmetric distance GEMM (64x64 tile, 4x4/thread) + block maxima --------
// Also emits M[n][blk] = max of each 64-col block of row n, computed from the
// exact STORED values (bit-consistent with what topk re-reads).
__global__ __launch_bounds__(256) void dist_sym64_k(
    const float* __restrict__ X0, int lda, int C,
    const float* __restrict__ sq0, float* __restrict__ D0,
    float* __restrict__ M0) {
  int t = blockIdx.x;
  int bi = 0;
  while (t >= 64 - bi) { t -= 64 - bi; ++bi; }
  const int bj = bi + t;
  const int b = blockIdx.y;
  const float* X = X0 + (size_t)b * NPTS * lda;
  const float* sq = sq0 + (size_t)b * NPTS;
  float* D = D0 + (size_t)b * NPTS * NPTS;
  float* M = M0 + (size_t)b * NPTS * 64;

  const int row0 = bi * 64, col0 = bj * 64;
  const int tid = threadIdx.x;
  const int tx = tid & 15, ty = tid >> 4;

  __shared__ __align__(16) float As[16][68];
  __shared__ __align__(16) float Bs[16][68];

  const int lr = tid >> 2;
  const int lc = (tid & 3) << 2;
  const float* Ap = X + (size_t)(row0 + lr) * lda + lc;
  const float* Bp = X + (size_t)(col0 + lr) * lda + lc;

  float acc[4][4] = {};
  for (int c0 = 0; c0 < C; c0 += 16) {
    float4 av = *(const float4*)(Ap + c0);
    float4 bv = *(const float4*)(Bp + c0);
    As[lc + 0][lr] = av.x; As[lc + 1][lr] = av.y;
    As[lc + 2][lr] = av.z; As[lc + 3][lr] = av.w;
    Bs[lc + 0][lr] = bv.x; Bs[lc + 1][lr] = bv.y;
    Bs[lc + 2][lr] = bv.z; Bs[lc + 3][lr] = bv.w;
    __syncthreads();
#pragma unroll
    for (int c = 0; c < 16; ++c) {
      float4 a4 = *(const float4*)(&As[c][ty << 2]);
      float4 b4 = *(const float4*)(&Bs[c][tx << 2]);
      float aa[4] = {a4.x, a4.y, a4.z, a4.w};
      float bb[4] = {b4.x, b4.y, b4.z, b4.w};
#pragma unroll
      for (int i = 0; i < 4; ++i)
#pragma unroll
        for (int j = 0; j < 4; ++j) acc[i][j] = fmaf(aa[i], bb[j], acc[i][j]);
    }
    __syncthreads();
  }

  float rs[4], cs[4];
#pragma unroll
  for (int i = 0; i < 4; ++i) rs[i] = sq[row0 + (ty << 2) + i];
#pragma unroll
  for (int j = 0; j < 4; ++j) cs[j] = sq[col0 + (tx << 2) + j];

  // direct store + per-row block max (reduce across the 16 tx lanes in-wave)
#pragma unroll
  for (int i = 0; i < 4; ++i) {
    const int row = row0 + (ty << 2) + i;
    float vals[4];
#pragma unroll
    for (int j = 0; j < 4; ++j) vals[j] = (2.0f * acc[i][j] - rs[i]) - cs[j];
    *(float4*)&D[(size_t)row * NPTS + col0 + (tx << 2)] =
        make_float4(vals[0], vals[1], vals[2], vals[3]);
    float rm = fmaxf(fmaxf(vals[0], vals[1]), fmaxf(vals[2], vals[3]));
    rm = fmaxf(rm, __shfl_xor(rm, 1));
    rm = fmaxf(rm, __shfl_xor(rm, 2));
    rm = fmaxf(rm, __shfl_xor(rm, 4));
    rm = fmaxf(rm, __shfl_xor(rm, 8));
    if (tx == 0) M[(size_t)row * 64 + bj] = rm;
  }

  if (bi != bj) {
    float cm4[4];
#pragma unroll
    for (int j = 0; j < 4; ++j) {
      const int col = col0 + (tx << 2) + j;
      float mv[4];
#pragma unroll
      for (int i = 0; i < 4; ++i) mv[i] = (2.0f * acc[i][j] - cs[j]) - rs[i];
      *(float4*)&D[(size_t)col * NPTS + row0 + (ty << 2)] =
          make_float4(mv[0], mv[1], mv[2], mv[3]);
      cm4[j] = fmaxf(fmaxf(mv[0], mv[1]), fmaxf(mv[2], mv[3]));
    }
    // mirror-row block max: reduce across ty via LDS (As reuse; GEMM done)
#pragma unroll
    for (int j = 0; j < 4; ++j) As[ty][(tx << 2) + j] = cm4[j];
    __syncthreads();
    const int colq = tid >> 2, q = tid & 3;
    float m = fmaxf(fmaxf(As[q * 4 + 0][colq], As[q * 4 + 1][colq]),
                    fmaxf(As[q * 4 + 2][colq], As[q * 4 + 3][colq]));
    m = fmaxf(m, __shfl_xor(m, 1));
    m = fmaxf(m, __shfl_xor(m, 2));
    if (q == 0) M[(size_t)(col0 + colq) * 64 + bi] = m;
  }
}

// ---------------- fused P/Q GEMM: P = A@Wd^T, Q = A@Wq^T + c0 ----------------
__global__ __launch_bounds__(256) void gemm_pq(
    const float* __restrict__ A, int lda,
    const float* __restrict__ Wd, const float* __restrict__ Wq, int ldb,
    float* __restrict__ P, float* __restrict__ Q, int ldo, int C,
    const float* __restrict__ c0b) {
  __shared__ __align__(16) float As[16][68];
  __shared__ __align__(16) float Bd[16][68];
  __shared__ __align__(16) float Bq[16][68];
  const int tx = threadIdx.x, ty = threadIdx.y;
  const int tid = ty * 16 + tx;
  const int row0 = blockIdx.y * 64, col0 = blockIdx.x * 64;
  const int lr = tid >> 2;
  const int lc = (tid & 3) << 2;
  const float* Ap = A + (size_t)(row0 + lr) * lda + lc;
  const float* Dp = Wd + (size_t)(col0 + lr) * ldb + lc;
  const float* Qp = Wq + (size_t)(col0 + lr) * ldb + lc;
  float accp[4][4] = {};
  float accq[4][4] = {};
  for (int c0 = 0; c0 < C; c0 += 16) {
    float4 av = *(const float4*)(Ap + c0);
    float4 dv = *(const float4*)(Dp + c0);
    float4 qv = *(const float4*)(Qp + c0);
    As[lc + 0][lr] = av.x; As[lc + 1][lr] = av.y;
    As[lc + 2][lr] = av.z; As[lc + 3][lr] = av.w;
    Bd[lc + 0][lr] = dv.x; Bd[lc + 1][lr] = dv.y;
    Bd[lc + 2][lr] = dv.z; Bd[lc + 3][lr] = dv.w;
    Bq[lc + 0][lr] = qv.x; Bq[lc + 1][lr] = qv.y;
    Bq[lc + 2][lr] = qv.z; Bq[lc + 3][lr] = qv.w;
    __syncthreads();
#pragma unroll
    for (int c = 0; c < 16; ++c) {
      float4 a4 = *(const float4*)(&As[c][ty << 2]);
      float4 d4 = *(const float4*)(&Bd[c][tx << 2]);
      float4 q4 = *(const float4*)(&Bq[c][tx << 2]);
      float aa[4] = {a4.x, a4.y, a4.z, a4.w};
      float dd[4] = {d4.x, d4.y, d4.z, d4.w};
      float qq[4] = {q4.x, q4.y, q4.z, q4.w};
#pragma unroll
      for (int i = 0; i < 4; ++i)
#pragma unroll
        for (int j = 0; j < 4; ++j) {
          accp[i][j] = fmaf(aa[i], dd[j], accp[i][j]);
          accq[i][j] = fmaf(aa[i], qq[j], accq[i][j]);
        }
    }
    __syncthreads();
  }
  const int row = row0 + (ty << 2), col = col0 + (tx << 2);
#pragma unroll
  for (int i = 0; i < 4; ++i) {
    *(float4*)(&P[(size_t)(row + i) * ldo + col]) = make_float4(
        accp[i][0], accp[i][1], accp[i][2], accp[i][3]);
    *(float4*)(&Q[(size_t)(row + i) * ldo + col]) = make_float4(
        accq[i][0] + c0b[col + 0], accq[i][1] + c0b[col + 1],
        accq[i][2] + c0b[col + 2], accq[i][3] + c0b[col + 3]);
  }
}

// ---------------- generic fp32 GEMM (dist fallback / head) ----------------
template <int EPI>
__global__ __launch_bounds__(256) void gemm_nt(
    const float* __restrict__ A, int lda,
    const float* __restrict__ Bm, int ldb,
    float* __restrict__ Out, int ldo, int C,
    const float* __restrict__ sqA, const float* __restrict__ sqB,
    const float* __restrict__ bias) {
  __shared__ __align__(16) float As[16][68];
  __shared__ __align__(16) float Bs[16][68];
  const int tx = threadIdx.x, ty = threadIdx.y;
  const int tid = ty * 16 + tx;
  const int row0 = blockIdx.y * 64, col0 = blockIdx.x * 64;
  const int lr = tid >> 2;
  const int lc = (tid & 3) << 2;
  const float* Ap = A + (size_t)(row0 + lr) * lda + lc;
  const float* Bp = Bm + (size_t)(col0 + lr) * ldb + lc;
  float acc[4][4] = {};
  for (int c0 = 0; c0 < C; c0 += 16) {
    float4 av = *(const float4*)(Ap + c0);
    float4 bv = *(const float4*)(Bp + c0);
    As[lc + 0][lr] = av.x; As[lc + 1][lr] = av.y;
    As[lc + 2][lr] = av.z; As[lc + 3][lr] = av.w;
    Bs[lc + 0][lr] = bv.x; Bs[lc + 1][lr] = bv.y;
    Bs[lc + 2][lr] = bv.z; Bs[lc + 3][lr] = bv.w;
    __syncthreads();
#pragma unroll
    for (int c = 0; c < 16; ++c) {
      float4 a4 = *(const float4*)(&As[c][ty << 2]);
      float4 b4 = *(const float4*)(&Bs[c][tx << 2]);
      float aa[4] = {a4.x, a4.y, a4.z, a4.w};
      float bb[4] = {b4.x, b4.y, b4.z, b4.w};
#pragma unroll
      for (int i = 0; i < 4; ++i)
#pragma unroll
        for (int j = 0; j < 4; ++j) acc[i][j] = fmaf(aa[i], bb[j], acc[i][j]);
    }
    __syncthreads();
  }
  const int row = row0 + (ty << 2), col = col0 + (tx << 2);
#pragma unroll
  for (int i = 0; i < 4; ++i) {
    float vals[4];
#pragma unroll
    for (int j = 0; j < 4; ++j) {
      float va = acc[i][j];
      if (EPI == 0) vals[j] = va;
      else if (EPI == 1) vals[j] = va + bias[col + j];
      else if (EPI == 2) vals[j] = 2.0f * va - sqA[row + i] - sqB[col + j];
      else { float t = va + bias[col + j]; vals[j] = t > 0.f ? t : 0.f; }
    }
    *(float4*)(&Out[(size_t)(row + i) * ldo + col]) =
        make_float4(vals[0], vals[1], vals[2], vals[3]);
  }
}

// ---------------- top-20 via block-max threshold (merged path) ----------------
// T = 20th-largest of the 64 block maxima of the row. Provably exact:
// >=20 values (the maxima) are >= T, so v20 >= T; every top-20 value lies in
// a block whose max >= T. Read only selected blocks, filter v >= T, then the
// verified candidate sort. Fallback: full-row re-read + topk_select<1>.
__global__ __launch_bounds__(256) void topk_blkmax(
    const float* __restrict__ D, long long dStride, const float* __restrict__ Mg,
    const float* __restrict__ P, const float* __restrict__ Q,
    float* __restrict__ Y, int ldy, int O) {
  const int tid = threadIdx.x;
  const int lane = tid & 63, wid = tid >> 6;
  const int n = blockIdx.x;
  const int b = blockIdx.y;
  const int bBase = b * NPTS;
  const float* drow = D + (size_t)b * (size_t)dStride + (size_t)n * NPTS;
  const float* mrow = Mg + ((size_t)(bBase + n)) * 64;

  __shared__ TopkShared sh;

  if (tid == 0) sh.cnt_s = 0;
  if (wid == 0) {
    float mval = mrow[lane];
    unsigned key = sort64_u32(f2u(mval), lane);
    unsigned tk = (unsigned)__shfl((int)key, 44);  // 20th largest
    bool pred = (f2u(mval) >= tk);
    unsigned long long bm = __ballot(pred);
    int pos = (int)__popcll(bm & ((1ull << lane) - 1ull));
    if (pred) sh.sblk[pos] = lane;
    if (lane == 0) { sh.nsel = (int)__popcll(bm); sh.tkey = tk; }
  }
  __syncthreads();
  const int ns = sh.nsel;
  const float Tvf = u2f(sh.tkey);

  for (int c0 = 0; c0 < ns; c0 += 4) {
    int bidx = c0 + wid;
    bool act = (bidx < ns);
    float v = -3.0e38f;
    int gcol = 0;
    if (act) {
      int blk = sh.sblk[bidx];
      gcol = (blk << 6) + lane;
      v = drow[gcol];
    }
    bool pred = act && (v >= Tvf);
    unsigned long long m = __ballot(pred);
    int below = (int)__popcll(m & ((1ull << lane) - 1ull));
    int cw = (int)__popcll(m);
    int base = 0;
    if (lane == 0 && cw) base = atomicAdd(&sh.cnt_s, cw);
    base = __shfl(base, 0);
    if (pred) {
      int pos = base + below;
      if (pos < 128) { sh.ck[pos] = f2u(v); sh.ci[pos] = gcol; }
    }
  }
  __syncthreads();
  const int cnt = sh.cnt_s;

  if (cnt <= 128) {
    if (wid == 0) {
      unsigned long long k0 = (lane < cnt)
          ? (((unsigned long long)sh.ck[lane] << 32) | (unsigned)(~sh.ci[lane])) : 0ull;
      if (cnt <= 64) {
        k0 = sort64_u64(k0, lane);
        if (lane >= 44) sh.selm[63 - lane] = (int)(~(unsigned)k0);
      } else {
        unsigned long long k1 = (64 + lane < cnt)
            ? (((unsigned long long)sh.ck[64 + lane] << 32) | (unsigned)(~sh.ci[64 + lane]))
            : 0ull;
        sort128_u64(k0, k1, lane);
        if (lane >= 44) sh.selm[63 - lane] = (int)(~(unsigned)k1);
      }
    }
    __syncthreads();
  } else {
    // fallback: full-row exact selection (verified path)
    float v[16];
#pragma unroll
    for (int c = 0; c < 4; ++c) {
      float4 f = *(const float4*)&drow[c * 1024 + tid * 4];
      v[c * 4 + 0] = f.x; v[c * 4 + 1] = f.y;
      v[c * 4 + 2] = f.z; v[c * 4 + 3] = f.w;
    }
    topk_select<1>(v, sh, tid, lane, wid);
  }

  topk_gather(sh, sh, P, Q, Y, ldy, O, bBase, n, tid, lane, wid);
}

// ---------------- standalone top-20 from materialized D (fallback path) ------
__global__ __launch_bounds__(256) void topk_max_f32(
    const float* __restrict__ D, long long dStride,
    const float* __restrict__ P, const float* __restrict__ Q,
    float* __restrict__ Y, int ldy, int O, int bBase0, int r0) {
  const int tid = threadIdx.x;
  const int lane = tid & 63, wid = tid >> 6;
  const int nloc = blockIdx.x;
  const int n = r0 + nloc;
  const int bBase = bBase0 + blockIdx.y * NPTS;
  const float* drow = D + (size_t)blockIdx.y * (size_t)dStride + (size_t)nloc * NPTS;
  __shared__ TopkShared sh;
  float v[16];
#pragma unroll
  for (int c = 0; c < 4; ++c) {
    float4 f = *(const float4*)&drow[c * 1024 + tid * 4];
    v[c * 4 + 0] = f.x; v[c * 4 + 1] = f.y;
    v[c * 4 + 2] = f.z; v[c * 4 + 3] = f.w;
  }
  topk_select<1>(v, sh, tid, lane, wid);
  topk_gather(sh, sh, P, Q, Y, ldy, O, bBase, n, tid, lane, wid);
}

// ---------------- final 128->1 dot ----------------
__global__ void final_dot_k(const float* __restrict__ h2, const float* __restrict__ w3,
                            const float* __restrict__ b3, float* __restrict__ out) {
  int gt = blockIdx.x * 256 + threadIdx.x;
  int row = gt >> 6, lane = gt & 63;
  float s = h2[(size_t)row * 128 + lane] * w3[lane] +
            h2[(size_t)row * 128 + 64 + lane] * w3[64 + lane];
#pragma unroll
  for (int off = 32; off > 0; off >>= 1) s += __shfl_down(s, off);
  if (lane == 0) out[row] = s + b3[0];
}

extern "C" void kernel_launch(void* const* d_in, const int* in_sizes, int n_in,
                              void* d_out, int out_size, void* d_ws, size_t ws_size,
                              hipStream_t stream) {
  const int B = 2, N = NPTS;
  const size_t NN = (size_t)N * N;
  const float* x = (const float*)d_in[0];
  const float* w[4]  = {(const float*)d_in[1], (const float*)d_in[6],
                        (const float*)d_in[11], (const float*)d_in[16]};
  const float* g[4]  = {(const float*)d_in[2], (const float*)d_in[7],
                        (const float*)d_in[12], (const float*)d_in[17]};
  const float* bt[4] = {(const float*)d_in[3], (const float*)d_in[8],
                        (const float*)d_in[13], (const float*)d_in[18]};
  const float* mm[4] = {(const float*)d_in[4], (const float*)d_in[9],
                        (const float*)d_in[14], (const float*)d_in[19]};
  const float* vv[4] = {(const float*)d_in[5], (const float*)d_in[10],
                        (const float*)d_in[15], (const float*)d_in[20]};
  const float* hw1 = (const float*)d_in[21]; const float* hb1 = (const float*)d_in[22];
  const float* hg1 = (const float*)d_in[23]; const float* hbt1 = (const float*)d_in[24];
  const float* hm1 = (const float*)d_in[25]; const float* hv1 = (const float*)d_in[26];
  const float* hw2 = (const float*)d_in[27]; const float* hb2 = (const float*)d_in[28];
  const float* hg2 = (const float*)d_in[29]; const float* hbt2 = (const float*)d_in[30];
  const float* hm2 = (const float*)d_in[31]; const float* hv2 = (const float*)d_in[32];
  const float* hw3 = (const float*)d_in[33]; const float* hb3 = (const float*)d_in[34];
  float* out = (float*)d_out;

  char* wsb = (char*)d_ws;
  size_t off = 0;
  auto alloc = [&](size_t nbytes) {
    char* p = wsb + off;
    off += (nbytes + 255) & ~(size_t)255;
    return p;
  };
  float* xc   = (float*)alloc((size_t)B * N * 512 * 4);
  float* P    = (float*)alloc((size_t)B * N * 256 * 4);
  float* Q    = (float*)alloc((size_t)B * N * 256 * 4);
  float* sq   = (float*)alloc((size_t)B * N * 4);
  float* wdf  = (float*)alloc(256 * 256 * 4);
  float* wqf  = (float*)alloc(256 * 256 * 4);
  float* c0   = (float*)alloc(256 * 4);
  float* hwf1 = (float*)alloc(256 * 512 * 4);
  float* cb1  = (float*)alloc(256 * 4);
  float* hwf2 = (float*)alloc(128 * 256 * 4);
  float* cb2  = (float*)alloc(128 * 4);
  float* Mg   = (float*)alloc((size_t)B * N * 64 * 4);
  float* D    = (float*)(wsb + off);
  size_t avail = (ws_size > off) ? (ws_size - off) : 0;
  const bool merged = (avail >= (size_t)B * NN * 4);
  int rows_tile = 4096;
  if (!merged)
    while ((size_t)rows_tile * N * 4 > avail && rows_tile > 64) rows_tile >>= 1;

  // dims = [(3,64), (64,64), (64,128), (128,256)]
  const int Cin[4]  = {3, 64, 64, 128};
  const int Oc[4]   = {64, 64, 128, 256};
  const int ioff[4] = {0, 0, 64, 128};
  const int ooff[4] = {0, 64, 128, 256};
  dim3 blk2(16, 16);

  for (int L = 0; L < 4; ++L) {
    const int C = Cin[L], O = Oc[L];
    const float* in = (L == 0) ? x : (xc + ioff[L]);
    const int lda = (L == 0) ? 3 : 512;

    fold_edge_k<<<dim3((O * C + 255) / 256), dim3(256), 0, stream>>>(
        w[L], g[L], bt[L], mm[L], vv[L], O, C, wdf, wqf, c0);
    sq_k<<<dim3((B * N + 255) / 256), dim3(256), 0, stream>>>(in, lda, C, sq, B * N);
    if (L == 0) {
      pq3_k<<<dim3(B * N * 64 / 256), dim3(256), 0, stream>>>(x, wdf, wqf, c0, P, Q);
    } else {
      gemm_pq<<<dim3(O / 64, B * N / 64), blk2, 0, stream>>>(
          in, lda, wdf, wqf, C, P, Q, O, C, c0);
    }

    if (L == 0) {
      topk_l1_fused<<<dim3(N, B), dim3(256), 0, stream>>>(
          x, sq, P, Q, xc + ooff[0], 512);
      continue;
    }
    if (merged) {
      dist_sym64_k<<<dim3(2080, B), dim3(256), 0, stream>>>(in, lda, C, sq, D, Mg);
      topk_blkmax<<<dim3(N, B), dim3(256), 0, stream>>>(
          D, (long long)NN, Mg, P, Q, xc + ooff[L], 512, O);
      continue;
    }
    for (int b = 0; b < B; ++b) {
      for (int r0 = 0; r0 < N; r0 += rows_tile) {
        gemm_nt<2><<<dim3(N / 64, rows_tile / 64), blk2, 0, stream>>>(
            in + ((size_t)b * N + r0) * lda, lda, in + (size_t)b * N * lda, lda,
            D, N, C, sq + b * N + r0, sq + b * N, nullptr);
        topk_max_f32<<<dim3(rows_tile, 1), dim3(256), 0, stream>>>(
            D, 0, P, Q, xc + ooff[L], 512, O, b * N, r0);
      }
    }
  }

  fold_head_k<<<dim3((256 * 512 + 255) / 256), dim3(256), 0, stream>>>(
      hw1, hb1, hg1, hbt1, hm1, hv1, 256, 512, hwf1, cb1);
  fold_head_k<<<dim3((128 * 256 + 255) / 256), dim3(256), 0, stream>>>(
      hw2, hb2, hg2, hbt2, hm2, hv2, 128, 256, hwf2, cb2);

  float* h1 = P;
  float* h2 = Q;
  gemm_nt<3><<<dim3(256 / 64, B * N / 64), blk2, 0, stream>>>(
      xc, 512, hwf1, 512, h1, 256, 512, nullptr, nullptr, cb1);
  gemm_nt<3><<<dim3(128 / 64, B * N / 64), blk2, 0, stream>>>(
      h1, 256, hwf2, 256, h2, 128, 256, nullptr, nullptr, cb2);
  final_dot_k<<<dim3(B * N / 4), dim3(256), 0, stream>>>(h2, hw3, hb3, out);
}